// Round 1
// baseline (76.073 us; speedup 1.0000x reference)
//
#include <hip/hip_runtime.h>
#include <math.h>

#define EPS_F 1e-8f

// ---------------------------------------------------------------------------
// lam_prep: lam[t] = max(tanh(raw_lambd[t]), EPS)  (tiny, L2-resident table)
// ---------------------------------------------------------------------------
__global__ void lam_prep_kernel(const float* __restrict__ raw_lambd,
                                float* __restrict__ lam_ws, int S) {
    int t = blockIdx.x * blockDim.x + threadIdx.x;
    if (t < S) lam_ws[t] = fmaxf(tanhf(raw_lambd[t]), EPS_F);
}

// ---------------------------------------------------------------------------
// Main scan: one 64-lane wave per batch row; lane l owns timesteps
// [l*32, l*32+32). Affine composition + wave-level Kogge-Stone suffix scan.
//   G_t = a_t + b_t * G_{t+1},  a_t = r + gamma(1-d)(1-lam)v_{t+1},
//                               b_t = gamma(1-d)lam,  G_S = v_S.
// ---------------------------------------------------------------------------
template <bool USE_WS>
__global__ __launch_bounds__(256) void glam_scan_kernel(
    const float* __restrict__ values,    // B x (S+1)
    const float* __restrict__ rewards,   // B x S
    const float* __restrict__ dones,     // B x S
    const float* __restrict__ raw_gamma, // 1
    const float* __restrict__ raw_lambd, // S
    const float* __restrict__ lam_ws,    // S (valid iff USE_WS)
    float* __restrict__ out,             // B x S
    int B, int S)
{
    constexpr int L = 32;                       // S must equal 64*L
    const int wave = (blockIdx.x * blockDim.x + threadIdx.x) >> 6;
    const int lane = threadIdx.x & 63;
    if (wave >= B) return;

    const float gamma = fmaxf(tanhf(raw_gamma[0]), EPS_F);

    const size_t vbase = (size_t)wave * (size_t)(S + 1);
    const size_t base  = (size_t)wave * (size_t)S;
    const int t0 = lane * L;

    float a[L], bb[L];

    // Build a[], b[] for this lane's chunk. rewards/dones rows are 16B-aligned
    // (S*4 % 16 == 0) -> float4 loads. values rows are only 4B-aligned
    // ((S+1)*4 % 16 != 0) -> scalar loads, unrolled back-to-back so the 16
    // loads sharing each 64B line merge in MSHRs (single HBM fetch per line).
    #pragma unroll
    for (int k = 0; k < L / 4; ++k) {
        const float4 r4 = *reinterpret_cast<const float4*>(rewards + base + t0 + 4 * k);
        const float4 d4 = *reinterpret_cast<const float4*>(dones   + base + t0 + 4 * k);
        const float rr[4] = { r4.x, r4.y, r4.z, r4.w };
        const float dd[4] = { d4.x, d4.y, d4.z, d4.w };
        #pragma unroll
        for (int j = 0; j < 4; ++j) {
            const int jj = 4 * k + j;
            const int t  = t0 + jj;
            const float v1 = values[vbase + t + 1];
            const float lt = USE_WS ? lam_ws[t]
                                    : fmaxf(tanhf(raw_lambd[t]), EPS_F);
            const float c  = gamma * (1.0f - dd[j]);
            a[jj]  = fmaf(c * (1.0f - lt), v1, rr[j]);
            bb[jj] = c * lt;
        }
    }

    // Lane-local backward composition: cur(x) = A + P*x over this chunk.
    float A = 0.0f, P = 1.0f;
    #pragma unroll
    for (int j = L - 1; j >= 0; --j) {
        A = fmaf(bb[j], A, a[j]);
        P *= bb[j];
    }

    // Wave-level Kogge-Stone SUFFIX scan: lane l ends with composition over
    // lanes l..63. combine(left, right) = (A_l + P_l*A_r, P_l*P_r).
    #pragma unroll
    for (int d = 1; d < 64; d <<= 1) {
        float A2 = __shfl_down(A, d);
        float P2 = __shfl_down(P, d);
        const bool valid = (lane + d) < 64;
        A2 = valid ? A2 : 0.0f;   // identity map beyond the wave
        P2 = valid ? P2 : 1.0f;
        A = fmaf(P, A2, A);
        P *= P2;
    }

    // Incoming boundary value for this lane's chunk: R_l = T_{l+1}(v_S).
    const float vS = values[vbase + S];     // bootstrap (broadcast load)
    const float A1 = __shfl_down(A, 1);
    const float P1 = __shfl_down(P, 1);
    float G = (lane == 63) ? vS : fmaf(P1, vS, A1);

    // Replay chunk with known incoming G; overwrite a[] with outputs.
    #pragma unroll
    for (int j = L - 1; j >= 0; --j) {
        G = fmaf(bb[j], G, a[j]);
        a[j] = G;
    }

    // Vectorized stores (out rows 16B-aligned).
    #pragma unroll
    for (int k = 0; k < L / 4; ++k) {
        float4 o4;
        o4.x = a[4 * k + 0];
        o4.y = a[4 * k + 1];
        o4.z = a[4 * k + 2];
        o4.w = a[4 * k + 3];
        *reinterpret_cast<float4*>(out + base + t0 + 4 * k) = o4;
    }
}

// ---------------------------------------------------------------------------
// Generic fallback (any S): one thread per row, sequential backward scan.
// ---------------------------------------------------------------------------
__global__ void glam_naive_kernel(const float* __restrict__ values,
                                  const float* __restrict__ rewards,
                                  const float* __restrict__ dones,
                                  const float* __restrict__ raw_gamma,
                                  const float* __restrict__ raw_lambd,
                                  float* __restrict__ out, int B, int S) {
    int b = blockIdx.x * blockDim.x + threadIdx.x;
    if (b >= B) return;
    const float gamma = fmaxf(tanhf(raw_gamma[0]), EPS_F);
    const size_t vbase = (size_t)b * (size_t)(S + 1);
    const size_t base  = (size_t)b * (size_t)S;
    float G = values[vbase + S];
    for (int t = S - 1; t >= 0; --t) {
        const float lt = fmaxf(tanhf(raw_lambd[t]), EPS_F);
        const float c  = gamma * (1.0f - dones[base + t]);
        G = rewards[base + t] + c * ((1.0f - lt) * values[vbase + t + 1] + lt * G);
        out[base + t] = G;
    }
}

extern "C" void kernel_launch(void* const* d_in, const int* in_sizes, int n_in,
                              void* d_out, int out_size, void* d_ws, size_t ws_size,
                              hipStream_t stream) {
    const float* values    = (const float*)d_in[0];
    const float* rewards   = (const float*)d_in[1];
    const float* dones     = (const float*)d_in[2];
    const float* raw_gamma = (const float*)d_in[3];
    const float* raw_lambd = (const float*)d_in[4];
    float* out = (float*)d_out;

    const int S = in_sizes[4];            // raw_lambd has S elements
    const int B = in_sizes[1] / S;        // rewards is B*S

    if (S != 64 * 32) {
        // Shape outside the tuned path: correctness fallback.
        glam_naive_kernel<<<(B + 255) / 256, 256, 0, stream>>>(
            values, rewards, dones, raw_gamma, raw_lambd, out, B, S);
        return;
    }

    const int total_threads = B * 64;     // one wave per row
    const int blocks = (total_threads + 255) / 256;

    const bool use_ws = (d_ws != nullptr) && (ws_size >= (size_t)S * sizeof(float));
    if (use_ws) {
        float* lam_ws = (float*)d_ws;
        lam_prep_kernel<<<(S + 255) / 256, 256, 0, stream>>>(raw_lambd, lam_ws, S);
        glam_scan_kernel<true><<<blocks, 256, 0, stream>>>(
            values, rewards, dones, raw_gamma, raw_lambd, lam_ws, out, B, S);
    } else {
        glam_scan_kernel<false><<<blocks, 256, 0, stream>>>(
            values, rewards, dones, raw_gamma, raw_lambd, nullptr, out, B, S);
    }
}

// Round 2
// 49.805 us; speedup vs baseline: 1.5274x; 1.5274x over previous
//
#include <hip/hip_runtime.h>
#include <math.h>

#define EPS_F 1e-8f

// ---------------------------------------------------------------------------
// lam_prep: lam[t] = max(tanh(raw_lambd[t]), EPS)  (tiny, L2-resident table)
// ---------------------------------------------------------------------------
__global__ void lam_prep_kernel(const float* __restrict__ raw_lambd,
                                float* __restrict__ lam_ws, int S) {
    int t = blockIdx.x * blockDim.x + threadIdx.x;
    if (t < S) lam_ws[t] = fmaxf(tanhf(raw_lambd[t]), EPS_F);
}

// ---------------------------------------------------------------------------
// Main scan: one 64-lane wave per batch row, processed in NP = S/256 passes
// from high t to low t. In pass p, lane l owns the 4 timesteps at
// t = p*256 + 4*l + j (j=0..3)  -> float4 loads/stores are FULLY coalesced
// (16B inter-lane stride). Per pass: affine compose (a,b), lane-local suffix
// compose, wave Kogge-Stone suffix scan, apply carry, replay, store. The
// scalar carry G (value at t = (p+1)*256) is broadcast from lane 0 between
// passes.
//   G_t = a_t + b_t * G_{t+1},  a_t = r + gamma(1-d)(1-lam)v_{t+1},
//                               b_t = gamma(1-d)lam,  G_S = v_S.
// ---------------------------------------------------------------------------
template <bool USE_WS>
__global__ __launch_bounds__(256) void glam_scan_kernel(
    const float* __restrict__ values,    // B x (S+1)
    const float* __restrict__ rewards,   // B x S
    const float* __restrict__ dones,     // B x S
    const float* __restrict__ raw_gamma, // 1
    const float* __restrict__ raw_lambd, // S
    const float* __restrict__ lam_ws,    // S (valid iff USE_WS)
    float* __restrict__ out,             // B x S
    int B, int S)
{
    const int wave = (blockIdx.x * blockDim.x + threadIdx.x) >> 6;
    const int lane = threadIdx.x & 63;
    if (wave >= B) return;

    const float gamma = fmaxf(tanhf(raw_gamma[0]), EPS_F);

    const size_t vbase = (size_t)wave * (size_t)(S + 1);
    const size_t base  = (size_t)wave * (size_t)S;

    const int NP = S >> 8;                 // passes of 256 timesteps
    float carry = values[vbase + S];       // bootstrap G at t = S

    #pragma unroll 8
    for (int p = NP - 1; p >= 0; --p) {
        const int c0 = p << 8;             // pass base timestep
        const int e0 = c0 + 4 * lane;      // this lane's first timestep

        // Coalesced float4 loads (16B inter-lane stride).
        const float4 r4 = *reinterpret_cast<const float4*>(rewards + base + e0);
        const float4 d4 = *reinterpret_cast<const float4*>(dones   + base + e0);

        float lamv[4];
        if (USE_WS) {
            const float4 l4 = *reinterpret_cast<const float4*>(lam_ws + e0);
            lamv[0] = l4.x; lamv[1] = l4.y; lamv[2] = l4.z; lamv[3] = l4.w;
        } else {
            #pragma unroll
            for (int j = 0; j < 4; ++j)
                lamv[j] = fmaxf(tanhf(raw_lambd[e0 + j]), EPS_F);
        }

        // values row is only 4B-aligned; scalar loads (16B lane stride,
        // lines fully consumed across the 4 unrolled instructions).
        float v1[4];
        #pragma unroll
        for (int j = 0; j < 4; ++j) v1[j] = values[vbase + e0 + j + 1];

        const float rr[4] = { r4.x, r4.y, r4.z, r4.w };
        const float dd[4] = { d4.x, d4.y, d4.z, d4.w };

        float a[4], bb[4];
        #pragma unroll
        for (int j = 0; j < 4; ++j) {
            const float c = gamma * (1.0f - dd[j]);
            a[j]  = fmaf(c * (1.0f - lamv[j]), v1[j], rr[j]);
            bb[j] = c * lamv[j];
        }

        // Lane-local backward composition over the 4 owned steps.
        float A = 0.0f, P = 1.0f;
        #pragma unroll
        for (int j = 3; j >= 0; --j) {
            A = fmaf(bb[j], A, a[j]);
            P *= bb[j];
        }

        // Wave Kogge-Stone SUFFIX scan: lane l -> composition over lanes l..63.
        #pragma unroll
        for (int d = 1; d < 64; d <<= 1) {
            float A2 = __shfl_down(A, d);
            float P2 = __shfl_down(P, d);
            const bool valid = (lane + d) < 64;
            A2 = valid ? A2 : 0.0f;        // identity beyond the wave
            P2 = valid ? P2 : 1.0f;
            A = fmaf(P, A2, A);
            P *= P2;
        }

        // Incoming G for this lane's chunk = suffix of lanes (l+1..63) applied
        // to the pass carry.
        const float A1 = __shfl_down(A, 1);
        const float P1 = __shfl_down(P, 1);
        float G = (lane == 63) ? carry : fmaf(P1, carry, A1);

        // Replay the 4 owned steps; collect outputs.
        float o[4];
        #pragma unroll
        for (int j = 3; j >= 0; --j) {
            G = fmaf(bb[j], G, a[j]);
            o[j] = G;
        }

        float4 o4;
        o4.x = o[0]; o4.y = o[1]; o4.z = o[2]; o4.w = o[3];
        *reinterpret_cast<float4*>(out + base + e0) = o4;   // coalesced store

        // Lane 0's final G is the value at t = p*256 -> carry for next pass.
        carry = __shfl(G, 0);
    }
}

// ---------------------------------------------------------------------------
// Generic fallback (any S): one thread per row, sequential backward scan.
// ---------------------------------------------------------------------------
__global__ void glam_naive_kernel(const float* __restrict__ values,
                                  const float* __restrict__ rewards,
                                  const float* __restrict__ dones,
                                  const float* __restrict__ raw_gamma,
                                  const float* __restrict__ raw_lambd,
                                  float* __restrict__ out, int B, int S) {
    int b = blockIdx.x * blockDim.x + threadIdx.x;
    if (b >= B) return;
    const float gamma = fmaxf(tanhf(raw_gamma[0]), EPS_F);
    const size_t vbase = (size_t)b * (size_t)(S + 1);
    const size_t base  = (size_t)b * (size_t)S;
    float G = values[vbase + S];
    for (int t = S - 1; t >= 0; --t) {
        const float lt = fmaxf(tanhf(raw_lambd[t]), EPS_F);
        const float c  = gamma * (1.0f - dones[base + t]);
        G = rewards[base + t] + c * ((1.0f - lt) * values[vbase + t + 1] + lt * G);
        out[base + t] = G;
    }
}

extern "C" void kernel_launch(void* const* d_in, const int* in_sizes, int n_in,
                              void* d_out, int out_size, void* d_ws, size_t ws_size,
                              hipStream_t stream) {
    const float* values    = (const float*)d_in[0];
    const float* rewards   = (const float*)d_in[1];
    const float* dones     = (const float*)d_in[2];
    const float* raw_gamma = (const float*)d_in[3];
    const float* raw_lambd = (const float*)d_in[4];
    float* out = (float*)d_out;

    const int S = in_sizes[4];            // raw_lambd has S elements
    const int B = in_sizes[1] / S;        // rewards is B*S

    if ((S & 255) != 0) {
        // Shape outside the tuned path: correctness fallback.
        glam_naive_kernel<<<(B + 255) / 256, 256, 0, stream>>>(
            values, rewards, dones, raw_gamma, raw_lambd, out, B, S);
        return;
    }

    const int total_threads = B * 64;     // one wave per row
    const int blocks = (total_threads + 255) / 256;

    const bool use_ws = (d_ws != nullptr) && (ws_size >= (size_t)S * sizeof(float));
    if (use_ws) {
        float* lam_ws = (float*)d_ws;
        lam_prep_kernel<<<(S + 255) / 256, 256, 0, stream>>>(raw_lambd, lam_ws, S);
        glam_scan_kernel<true><<<blocks, 256, 0, stream>>>(
            values, rewards, dones, raw_gamma, raw_lambd, lam_ws, out, B, S);
    } else {
        glam_scan_kernel<false><<<blocks, 256, 0, stream>>>(
            values, rewards, dones, raw_gamma, raw_lambd, nullptr, out, B, S);
    }
}

// Round 3
// 49.152 us; speedup vs baseline: 1.5477x; 1.0133x over previous
//
#include <hip/hip_runtime.h>
#include <math.h>

#define EPS_F 1e-8f

typedef float vfloat4 __attribute__((ext_vector_type(4)));

// ---------------------------------------------------------------------------
// lam_prep: lam[t] = max(tanh(raw_lambd[t]), EPS)  (tiny, L2-resident table)
// ---------------------------------------------------------------------------
__global__ void lam_prep_kernel(const float* __restrict__ raw_lambd,
                                float* __restrict__ lam_ws, int S) {
    int t = blockIdx.x * blockDim.x + threadIdx.x;
    if (t < S) lam_ws[t] = fmaxf(tanhf(raw_lambd[t]), EPS_F);
}

// ---------------------------------------------------------------------------
// Main scan: one 64-lane wave per batch row, NP = S/256 passes from high t to
// low t. In pass p, lane l owns t = p*256 + 4l + j (j=0..3) -> float4
// loads/stores fully coalesced. Depth-2 software pipeline: pass p-1's loads
// are issued BEFORE pass p's data is consumed, so each wave always has one
// pass of loads in flight while scanning (counted-vmcnt rotate pattern).
// Output stores are non-temporal (write-once, never re-read) to keep the
// 64 MB output from evicting L2/L3 input lines.
//   G_t = a_t + b_t * G_{t+1},  a_t = r + gamma(1-d)(1-lam)v_{t+1},
//                               b_t = gamma(1-d)lam,  G_S = v_S.
// ---------------------------------------------------------------------------
template <bool USE_WS>
__global__ __launch_bounds__(256) void glam_scan_kernel(
    const float* __restrict__ values,    // B x (S+1)
    const float* __restrict__ rewards,   // B x S
    const float* __restrict__ dones,     // B x S
    const float* __restrict__ raw_gamma, // 1
    const float* __restrict__ raw_lambd, // S
    const float* __restrict__ lam_ws,    // S (valid iff USE_WS)
    float* __restrict__ out,             // B x S
    int B, int S)
{
    const int wave = (blockIdx.x * blockDim.x + threadIdx.x) >> 6;
    const int lane = threadIdx.x & 63;
    if (wave >= B) return;

    const float gamma = fmaxf(tanhf(raw_gamma[0]), EPS_F);

    const size_t vbase = (size_t)wave * (size_t)(S + 1);
    const size_t base  = (size_t)wave * (size_t)S;

    const int NP  = S >> 8;              // passes of 256 timesteps
    const int lo4 = 4 * lane;

    float carry = values[vbase + S];     // bootstrap G at t = S

    // ---- Prologue: issue loads for pass NP-1 ----
    int pe0 = ((NP - 1) << 8) + lo4;
    vfloat4 nr = *reinterpret_cast<const vfloat4*>(rewards + base + pe0);
    vfloat4 nd = *reinterpret_cast<const vfloat4*>(dones   + base + pe0);
    float   nl[4];
    if (USE_WS) {
        vfloat4 l4 = *reinterpret_cast<const vfloat4*>(lam_ws + pe0);
        nl[0] = l4.x; nl[1] = l4.y; nl[2] = l4.z; nl[3] = l4.w;
    } else {
        #pragma unroll
        for (int j = 0; j < 4; ++j)
            nl[j] = fmaxf(tanhf(raw_lambd[pe0 + j]), EPS_F);
    }
    float nv[4];
    #pragma unroll
    for (int j = 0; j < 4; ++j) nv[j] = values[vbase + pe0 + 1 + j];

    #pragma unroll 1
    for (int p = NP - 1; p >= 0; --p) {
        // ---- Rotate: stash the in-flight pass-p data ----
        const float cr[4] = { nr.x, nr.y, nr.z, nr.w };
        const float cd[4] = { nd.x, nd.y, nd.z, nd.w };
        float cl[4], cv[4];
        #pragma unroll
        for (int j = 0; j < 4; ++j) { cl[j] = nl[j]; cv[j] = nv[j]; }
        const int ce0 = (p << 8) + lo4;

        // ---- Prefetch pass p-1 (issued before consuming pass p) ----
        if (p > 0) {
            const int ne0 = ((p - 1) << 8) + lo4;
            nr = *reinterpret_cast<const vfloat4*>(rewards + base + ne0);
            nd = *reinterpret_cast<const vfloat4*>(dones   + base + ne0);
            if (USE_WS) {
                vfloat4 l4 = *reinterpret_cast<const vfloat4*>(lam_ws + ne0);
                nl[0] = l4.x; nl[1] = l4.y; nl[2] = l4.z; nl[3] = l4.w;
            } else {
                #pragma unroll
                for (int j = 0; j < 4; ++j)
                    nl[j] = fmaxf(tanhf(raw_lambd[ne0 + j]), EPS_F);
            }
            #pragma unroll
            for (int j = 0; j < 4; ++j) nv[j] = values[vbase + ne0 + 1 + j];
        }

        // ---- Build affine coefficients for the 4 owned steps ----
        float a[4], bb[4];
        #pragma unroll
        for (int j = 0; j < 4; ++j) {
            const float c = gamma * (1.0f - cd[j]);
            a[j]  = fmaf(c * (1.0f - cl[j]), cv[j], cr[j]);
            bb[j] = c * cl[j];
        }

        // ---- Lane-local backward composition ----
        float A = 0.0f, P = 1.0f;
        #pragma unroll
        for (int j = 3; j >= 0; --j) {
            A = fmaf(bb[j], A, a[j]);
            P *= bb[j];
        }

        // ---- Wave Kogge-Stone SUFFIX scan (lane l -> lanes l..63) ----
        #pragma unroll
        for (int d = 1; d < 64; d <<= 1) {
            float A2 = __shfl_down(A, d);
            float P2 = __shfl_down(P, d);
            const bool valid = (lane + d) < 64;
            A2 = valid ? A2 : 0.0f;      // identity beyond the wave
            P2 = valid ? P2 : 1.0f;
            A = fmaf(P, A2, A);
            P *= P2;
        }

        // ---- Incoming G for this lane = suffix of lanes (l+1..63) o carry ----
        const float A1 = __shfl_down(A, 1);
        const float P1 = __shfl_down(P, 1);
        float G = (lane == 63) ? carry : fmaf(P1, carry, A1);

        // ---- Replay the 4 owned steps ----
        float o[4];
        #pragma unroll
        for (int j = 3; j >= 0; --j) {
            G = fmaf(bb[j], G, a[j]);
            o[j] = G;
        }

        vfloat4 o4;
        o4.x = o[0]; o4.y = o[1]; o4.z = o[2]; o4.w = o[3];
        __builtin_nontemporal_store(o4,
            reinterpret_cast<vfloat4*>(out + base + ce0));

        // Lane 0's final G is the value at t = p*256 -> carry for next pass.
        carry = __shfl(G, 0);
    }
}

// ---------------------------------------------------------------------------
// Generic fallback (any S): one thread per row, sequential backward scan.
// ---------------------------------------------------------------------------
__global__ void glam_naive_kernel(const float* __restrict__ values,
                                  const float* __restrict__ rewards,
                                  const float* __restrict__ dones,
                                  const float* __restrict__ raw_gamma,
                                  const float* __restrict__ raw_lambd,
                                  float* __restrict__ out, int B, int S) {
    int b = blockIdx.x * blockDim.x + threadIdx.x;
    if (b >= B) return;
    const float gamma = fmaxf(tanhf(raw_gamma[0]), EPS_F);
    const size_t vbase = (size_t)b * (size_t)(S + 1);
    const size_t base  = (size_t)b * (size_t)S;
    float G = values[vbase + S];
    for (int t = S - 1; t >= 0; --t) {
        const float lt = fmaxf(tanhf(raw_lambd[t]), EPS_F);
        const float c  = gamma * (1.0f - dones[base + t]);
        G = rewards[base + t] + c * ((1.0f - lt) * values[vbase + t + 1] + lt * G);
        out[base + t] = G;
    }
}

extern "C" void kernel_launch(void* const* d_in, const int* in_sizes, int n_in,
                              void* d_out, int out_size, void* d_ws, size_t ws_size,
                              hipStream_t stream) {
    const float* values    = (const float*)d_in[0];
    const float* rewards   = (const float*)d_in[1];
    const float* dones     = (const float*)d_in[2];
    const float* raw_gamma = (const float*)d_in[3];
    const float* raw_lambd = (const float*)d_in[4];
    float* out = (float*)d_out;

    const int S = in_sizes[4];            // raw_lambd has S elements
    const int B = in_sizes[1] / S;        // rewards is B*S

    if ((S & 255) != 0) {
        // Shape outside the tuned path: correctness fallback.
        glam_naive_kernel<<<(B + 255) / 256, 256, 0, stream>>>(
            values, rewards, dones, raw_gamma, raw_lambd, out, B, S);
        return;
    }

    const int total_threads = B * 64;     // one wave per row
    const int blocks = (total_threads + 255) / 256;

    const bool use_ws = (d_ws != nullptr) && (ws_size >= (size_t)S * sizeof(float));
    if (use_ws) {
        float* lam_ws = (float*)d_ws;
        lam_prep_kernel<<<(S + 255) / 256, 256, 0, stream>>>(raw_lambd, lam_ws, S);
        glam_scan_kernel<true><<<blocks, 256, 0, stream>>>(
            values, rewards, dones, raw_gamma, raw_lambd, lam_ws, out, B, S);
    } else {
        glam_scan_kernel<false><<<blocks, 256, 0, stream>>>(
            values, rewards, dones, raw_gamma, raw_lambd, nullptr, out, B, S);
    }
}